// Round 7
// baseline (277.323 us; speedup 1.0000x reference)
//
#include <hip/hip_runtime.h>
#include <math.h>

#define B_ 16
#define T_ 2048
#define D_ 256
#define W_ 128
#define M_ (B_*T_)   // 32768

typedef __attribute__((ext_vector_type(8))) short bf16x8;
typedef __attribute__((ext_vector_type(4))) float f32x4;
typedef unsigned short u16;

static __device__ __forceinline__ u16 f32_bf16_rne(float f) {
    unsigned int u = __float_as_uint(f);
    u += 0x7FFF + ((u >> 16) & 1);
    return (u16)(u >> 16);
}
static __device__ __forceinline__ float bf16_f32(u16 h) {
    return __uint_as_float(((unsigned int)h) << 16);
}

// ---------------------------------------------------------------------------
// K0: transpose weights to bf16 [mat][n][k]: hi for all 4 mats; lo for Wk only
// (k feeds exp -> keep 3-term split; q/v/Wo are single-bf16: their outputs
// are stored as bf16 downstream anyway, so input rounding is subdominant).
// ---------------------------------------------------------------------------
__global__ __launch_bounds__(256) void aft_split_wT(
    const float* __restrict__ Wq, const float* __restrict__ Wk,
    const float* __restrict__ Wv, const float* __restrict__ Wo,
    u16* __restrict__ Wth, u16* __restrict__ Wkl)
{
    const float* Ws[4] = {Wq, Wk, Wv, Wo};
    const float* W = Ws[blockIdx.x];
    const int n  = blockIdx.y * 16 + (threadIdx.x >> 4);
    const int k0 = (threadIdx.x & 15) * 16;
    size_t obase = ((size_t)blockIdx.x * 256 + n) * 256 + k0;
    #pragma unroll 4
    for (int j = 0; j < 16; ++j) {
        float v = W[(size_t)(k0 + j) * 256 + n];
        u16 h = f32_bf16_rne(v);
        Wth[obase + j] = h;
        if (blockIdx.x == 1)
            Wkl[(size_t)n * 256 + k0 + j] = f32_bf16_rne(v - bf16_f32(h));
    }
}

// ---------------------------------------------------------------------------
// K0b: banded EW precompute. EWb[t][j], j in [0,320): exp(wb[t][s])-1 inside
// band else 0, s = (t & ~63) - 128 + j.  bf16.
// ---------------------------------------------------------------------------
__global__ void aft_ewb(const float* __restrict__ wb, u16* __restrict__ EWb)
{
    const int t = blockIdx.x;
    const int j = threadIdx.x;   // blockDim = 320
    const int s = (t & ~63) - 128 + j;
    const int dlt = s - t;
    float v = 0.f;
    if (s >= 0 && s < T_ && dlt > -W_ && dlt < W_)
        v = expf(wb[(size_t)t * T_ + s]) - 1.0f;
    EWb[(size_t)t * 320 + j] = f32_bf16_rne(v);
}

// ---------------------------------------------------------------------------
// K1: QKV projections.  q = xh*Wqh (1 MFMA), k = 3-term split, v = xh*Wvh.
// 128 rows x 64 cols x 3 mats per block; in-kernel fp32->bf16 split of x
// (R4-proven staging: pad-40 rows, no swizzle, VGPR-roundtrip so the
// compiler pipelines next-chunk loads across the barrier).
// Epilogue: LDS-transpose to ekT[b][n][s] (n<256 ek, n>=256 ekv) and
// sigqT[b][d][t] bf16, with Sk/Sv partial sums fused via atomicAdd.
// ---------------------------------------------------------------------------
__global__ __launch_bounds__(256) void aft_qkv_mfma(
    const float* __restrict__ x,
    const u16* __restrict__ Wth, const u16* __restrict__ Wkl,
    u16* __restrict__ ekT, u16* __restrict__ sigqT,
    float* __restrict__ Sk, float* __restrict__ Sv)
{
    __shared__ alignas(16) u16 sm[20480];   // 40 KiB -> 4 blocks/CU
    u16* Ah = sm;              // [128][40]
    u16* Al = sm + 5120;
    u16* Bs = sm + 10240;      // [4][64][40]: Wqh, Wkh, Wkl, Wvh
    u16* Tr = sm;              // [64][136] epilogue reuse

    const int tid  = threadIdx.x;
    const int row0 = blockIdx.x * 128;
    const int col0 = blockIdx.y * 64;
    const int b    = row0 >> 11;
    const int t0g  = row0 & (T_ - 1);
    const int lane = tid & 63;
    const int wid  = tid >> 6;
    const int wm   = (wid & 1) * 64;
    const int wn   = (wid >> 1) * 32;
    const int qd   = lane >> 4;
    const int r    = lane & 15;

    f32x4 accq[4][2], acck[4][2], accv[4][2];
    #pragma unroll
    for (int i = 0; i < 4; ++i)
        #pragma unroll
        for (int j = 0; j < 2; ++j) {
            accq[i][j] = (f32x4){0.f, 0.f, 0.f, 0.f};
            acck[i][j] = accq[i][j];
            accv[i][j] = accq[i][j];
        }

    const int am   = tid >> 1;          // 0..127
    const int akh  = (tid & 1) * 16;    // 0 / 16
    const int brow = tid >> 2;          // 0..63
    const int bseg = (tid & 3) * 8;     // 0,8,16,24

    for (int k0 = 0; k0 < D_; k0 += 32) {
        // stage A: fp32 x -> bf16 hi/lo in-kernel
        {
            size_t g = (size_t)(row0 + am) * D_ + k0 + akh;
            union { ushort4 s4[4]; u16 h[16]; } H, L;
            #pragma unroll
            for (int c = 0; c < 4; ++c) {
                float4 v = *(const float4*)&x[g + c * 4];
                float vv[4] = {v.x, v.y, v.z, v.w};
                #pragma unroll
                for (int e = 0; e < 4; ++e) {
                    u16 h = f32_bf16_rne(vv[e]);
                    H.h[c * 4 + e] = h;
                    L.h[c * 4 + e] = f32_bf16_rne(vv[e] - bf16_f32(h));
                }
            }
            *(ushort4*)&Ah[am * 40 + akh]      = H.s4[0];
            *(ushort4*)&Ah[am * 40 + akh + 4]  = H.s4[1];
            *(ushort4*)&Ah[am * 40 + akh + 8]  = H.s4[2];
            *(ushort4*)&Ah[am * 40 + akh + 12] = H.s4[3];
            *(ushort4*)&Al[am * 40 + akh]      = L.s4[0];
            *(ushort4*)&Al[am * 40 + akh + 4]  = L.s4[1];
            *(ushort4*)&Al[am * 40 + akh + 8]  = L.s4[2];
            *(ushort4*)&Al[am * 40 + akh + 12] = L.s4[3];
        }
        // stage B: Wqh, Wkh, Wkl, Wvh  (64 rows x 32 k each)
        {
            size_t nrow = (size_t)(col0 + brow) * 256 + k0 + bseg;
            uint4 vq  = *(const uint4*)&Wth[nrow];                 // mat 0 hi
            uint4 vkh = *(const uint4*)&Wth[65536 + nrow];         // mat 1 hi
            uint4 vkl = *(const uint4*)&Wkl[nrow];                 // mat 1 lo
            uint4 vv  = *(const uint4*)&Wth[2 * 65536 + nrow];     // mat 2 hi
            *(uint4*)&Bs[0 * 2560 + brow * 40 + bseg] = vq;
            *(uint4*)&Bs[1 * 2560 + brow * 40 + bseg] = vkh;
            *(uint4*)&Bs[2 * 2560 + brow * 40 + bseg] = vkl;
            *(uint4*)&Bs[3 * 2560 + brow * 40 + bseg] = vv;
        }
        __syncthreads();

        bf16x8 ah[4], al[4];
        #pragma unroll
        for (int mf = 0; mf < 4; ++mf) {
            ah[mf] = *(const bf16x8*)&Ah[(wm + mf * 16 + r) * 40 + qd * 8];
            al[mf] = *(const bf16x8*)&Al[(wm + mf * 16 + r) * 40 + qd * 8];
        }
        #pragma unroll
        for (int nf = 0; nf < 2; ++nf) {
            int br = (wn + nf * 16 + r) * 40 + qd * 8;
            bf16x8 bq  = *(const bf16x8*)&Bs[br];
            bf16x8 bkh = *(const bf16x8*)&Bs[2560 + br];
            bf16x8 bkl = *(const bf16x8*)&Bs[5120 + br];
            bf16x8 bv  = *(const bf16x8*)&Bs[7680 + br];
            #pragma unroll
            for (int mf = 0; mf < 4; ++mf) {
                accq[mf][nf] = __builtin_amdgcn_mfma_f32_16x16x32_bf16(ah[mf], bq,  accq[mf][nf], 0, 0, 0);
                acck[mf][nf] = __builtin_amdgcn_mfma_f32_16x16x32_bf16(ah[mf], bkh, acck[mf][nf], 0, 0, 0);
                acck[mf][nf] = __builtin_amdgcn_mfma_f32_16x16x32_bf16(ah[mf], bkl, acck[mf][nf], 0, 0, 0);
                acck[mf][nf] = __builtin_amdgcn_mfma_f32_16x16x32_bf16(al[mf], bkh, acck[mf][nf], 0, 0, 0);
                accv[mf][nf] = __builtin_amdgcn_mfma_f32_16x16x32_bf16(ah[mf], bv,  accv[mf][nf], 0, 0, 0);
            }
        }
        __syncthreads();
    }

    // epilogue: 3 LDS-transpose rounds (ek, ekv, sigq); Sk/Sv fused atomics.
    const int dl_r = tid >> 2;            // 0..63  (local col)
    const int tseg = (tid & 3) * 32;      // 0..96  (t segment)
    #pragma unroll
    for (int round = 0; round < 3; ++round) {
        __syncthreads();
        #pragma unroll
        for (int mf = 0; mf < 4; ++mf) {
            #pragma unroll
            for (int nf = 0; nf < 2; ++nf) {
                ushort4 o;
                float vals[4];
                #pragma unroll
                for (int reg = 0; reg < 4; ++reg) {
                    if (round == 0)      vals[reg] = expf(acck[mf][nf][reg]);
                    else if (round == 1) vals[reg] = expf(acck[mf][nf][reg]) * accv[mf][nf][reg];
                    else                 vals[reg] = 1.f / (1.f + expf(-accq[mf][nf][reg]));
                }
                o.x = f32_bf16_rne(vals[0]); o.y = f32_bf16_rne(vals[1]);
                o.z = f32_bf16_rne(vals[2]); o.w = f32_bf16_rne(vals[3]);
                int dl = wn + nf * 16 + r;
                int tt = wm + mf * 16 + qd * 4;
                *(ushort4*)&Tr[dl * 136 + tt] = o;
            }
        }
        __syncthreads();
        u16* dst;
        if (round == 0)      dst = ekT   + ((size_t)(b * 512 + col0 + dl_r)) * 2048;
        else if (round == 1) dst = ekT   + ((size_t)(b * 512 + 256 + col0 + dl_r)) * 2048;
        else                 dst = sigqT + ((size_t)(b * 256 + col0 + dl_r)) * 2048;
        dst += t0g + tseg;
        union { uint4 v; u16 h[8]; } u[4];
        #pragma unroll
        for (int i = 0; i < 4; ++i)
            u[i].v = *(const uint4*)&Tr[dl_r * 136 + tseg + i * 8];
        if (round < 2) {
            float lsum = 0.f;
            #pragma unroll
            for (int i = 0; i < 4; ++i)
                #pragma unroll
                for (int j = 0; j < 8; ++j)
                    lsum += bf16_f32(u[i].h[j]);
            if (round == 0) atomicAdd(&Sk[b * 256 + col0 + dl_r], lsum);
            else            atomicAdd(&Sv[b * 256 + col0 + dl_r], lsum);
        }
        #pragma unroll
        for (int i = 0; i < 4; ++i)
            *(uint4*)&dst[i * 8] = u[i].v;
    }
}

// ---------------------------------------------------------------------------
// K3: banded num/den via bf16 MFMA.  Block = 64 t x 128 d; wave 64t x 32d
// holds num+den.  Epilogue: y = sig(q)*(Sv+num)/(Sk+den), LDS-transposed to
// y[b][t][d] bf16 so the out-GEMM stages A with vector ops.
// ---------------------------------------------------------------------------
__global__ __launch_bounds__(256) void aft_band_mfma(
    const u16* __restrict__ EWb, const u16* __restrict__ ekT,
    const u16* __restrict__ sigqT,
    const float* __restrict__ Sk, const float* __restrict__ Sv,
    u16* __restrict__ yTD)
{
    __shared__ alignas(16) u16 sm[12800];
    u16* Aw  = sm;          // [64][40]
    u16* Bkv = sm + 2560;   // [256][40] : rows 0..127 ek, 128..255 ekv

    const int tid  = threadIdx.x;
    const int t0   = blockIdx.x * 64;
    const int b    = blockIdx.y >> 1;
    const int dh   = (blockIdx.y & 1) * 128;
    const int lane = tid & 63;
    const int wid  = tid >> 6;
    const int wn   = wid * 32;
    const int qd   = lane >> 4;
    const int r    = lane & 15;

    f32x4 accn[4][2], accd[4][2];
    #pragma unroll
    for (int i = 0; i < 4; ++i)
        #pragma unroll
        for (int j = 0; j < 2; ++j) {
            accn[i][j] = (f32x4){0.f, 0.f, 0.f, 0.f};
            accd[i][j] = (f32x4){0.f, 0.f, 0.f, 0.f};
        }

    const int atl = tid >> 2;          // 0..63
    const int ak8 = (tid & 3) * 8;     // 0,8,16,24

    for (int c = 0; c < 10; ++c) {
        const int sc = t0 - 128 + c * 32;
        if (sc < 0 || sc >= T_) continue;   // uniform per block; EW there is 0
        __syncthreads();
        *(uint4*)&Aw[atl * 40 + ak8] =
            *(const uint4*)&EWb[(size_t)(t0 + atl) * 320 + c * 32 + ak8];
        #pragma unroll
        for (int rr = 0; rr < 4; ++rr) {
            int nl = rr * 64 + atl;                        // 0..255
            int n  = (nl < 128) ? (dh + nl) : (256 + dh + nl - 128);
            *(uint4*)&Bkv[nl * 40 + ak8] =
                *(const uint4*)&ekT[((size_t)(b * 512) + n) * 2048 + sc + ak8];
        }
        __syncthreads();

        bf16x8 af[4];
        #pragma unroll
        for (int mf = 0; mf < 4; ++mf)
            af[mf] = *(const bf16x8*)&Aw[(mf * 16 + r) * 40 + qd * 8];
        #pragma unroll
        for (int nf = 0; nf < 2; ++nf) {
            bf16x8 be = *(const bf16x8*)&Bkv[(wn + nf * 16 + r) * 40 + qd * 8];
            bf16x8 bv = *(const bf16x8*)&Bkv[(128 + wn + nf * 16 + r) * 40 + qd * 8];
            #pragma unroll
            for (int mf = 0; mf < 4; ++mf) {
                accd[mf][nf] = __builtin_amdgcn_mfma_f32_16x16x32_bf16(af[mf], be, accd[mf][nf], 0, 0, 0);
                accn[mf][nf] = __builtin_amdgcn_mfma_f32_16x16x32_bf16(af[mf], bv, accn[mf][nf], 0, 0, 0);
            }
        }
    }

    // epilogue: y into LDS [t_local][136] then coalesced store to y[b][t][d]
    __syncthreads();
    u16* Ly = sm;    // [64][136]
    #pragma unroll
    for (int nf = 0; nf < 2; ++nf) {
        const int dl = wn + nf * 16 + r;
        const int d  = dh + dl;
        const float skq = Sk[(b << 8) + d];
        const float svq = Sv[(b << 8) + d];
        #pragma unroll
        for (int mf = 0; mf < 4; ++mf) {
            const int tt = t0 + mf * 16 + qd * 4;
            size_t off = ((size_t)(b << 8) + d) * 2048 + tt;
            ushort4 sg = *(const ushort4*)&sigqT[off];
            float s4[4] = {bf16_f32(sg.x), bf16_f32(sg.y), bf16_f32(sg.z), bf16_f32(sg.w)};
            #pragma unroll
            for (int reg = 0; reg < 4; ++reg) {
                float y = s4[reg] * (svq + accn[mf][nf][reg]) / (skq + accd[mf][nf][reg]);
                Ly[(mf * 16 + qd * 4 + reg) * 136 + dl] = f32_bf16_rne(y);
            }
        }
    }
    __syncthreads();
    {
        const int tl  = tid >> 2;          // 0..63
        const int ds4 = (tid & 3) * 32;    // 0..96
        u16* dst = yTD + ((size_t)b * 2048 + t0 + tl) * 256 + dh + ds4;
        #pragma unroll
        for (int i = 0; i < 4; ++i)
            *(uint4*)&dst[i * 8] = *(const uint4*)&Ly[tl * 136 + ds4 + i * 8];
    }
}

// ---------------------------------------------------------------------------
// K4: out = y @ Wo, single-bf16 both sides.  64 rows x 128 cols per block,
// grid (512, 2).  A staged from y[b][t][d] with vector loads/writes.
// ---------------------------------------------------------------------------
__global__ __launch_bounds__(256) void aft_out_mfma(
    const u16* __restrict__ yTD, const u16* __restrict__ Woth,
    float* __restrict__ out)
{
    __shared__ alignas(16) u16 sm[7680];
    u16* As = sm;           // [64][40]
    u16* Bh = sm + 2560;    // [128][40]

    const int tid  = threadIdx.x;
    const int row0 = blockIdx.x * 64;
    const int col0 = blockIdx.y * 128;
    const int lane = tid & 63;
    const int wid  = tid >> 6;
    const int wn   = wid * 32;
    const int qd   = lane >> 4;
    const int r    = lane & 15;

    f32x4 acc[4][2];
    #pragma unroll
    for (int i = 0; i < 4; ++i)
        #pragma unroll
        for (int j = 0; j < 2; ++j)
            acc[i][j] = (f32x4){0.f, 0.f, 0.f, 0.f};

    const int arow = tid >> 2;          // 0..63
    const int aseg = (tid & 3) * 8;
    const int brw  = tid >> 1;          // 0..127
    const int bsg  = (tid & 1) * 16;

    for (int k0 = 0; k0 < D_; k0 += 32) {
        {
            uint4 v = *(const uint4*)&yTD[(size_t)(row0 + arow) * 256 + k0 + aseg];
            *(uint4*)&As[arow * 40 + aseg] = v;
        }
        {
            size_t g = (size_t)(col0 + brw) * 256 + k0 + bsg;
            uint4 v0 = *(const uint4*)&Woth[g];
            uint4 v1 = *(const uint4*)&Woth[g + 8];
            *(uint4*)&Bh[brw * 40 + bsg]     = v0;
            *(uint4*)&Bh[brw * 40 + bsg + 8] = v1;
        }
        __syncthreads();

        bf16x8 af[4];
        #pragma unroll
        for (int mf = 0; mf < 4; ++mf)
            af[mf] = *(const bf16x8*)&As[(mf * 16 + r) * 40 + qd * 8];
        #pragma unroll
        for (int nf = 0; nf < 2; ++nf) {
            bf16x8 bh = *(const bf16x8*)&Bh[(wn + nf * 16 + r) * 40 + qd * 8];
            #pragma unroll
            for (int mf = 0; mf < 4; ++mf)
                acc[mf][nf] = __builtin_amdgcn_mfma_f32_16x16x32_bf16(af[mf], bh, acc[mf][nf], 0, 0, 0);
        }
        __syncthreads();
    }

    #pragma unroll
    for (int mf = 0; mf < 4; ++mf)
        #pragma unroll
        for (int nf = 0; nf < 2; ++nf)
            #pragma unroll
            for (int reg = 0; reg < 4; ++reg) {
                int mrow = row0 + mf * 16 + qd * 4 + reg;
                int ncol = col0 + wn + nf * 16 + r;
                out[(size_t)mrow * D_ + ncol] = acc[mf][nf][reg];
            }
}

extern "C" void kernel_launch(void* const* d_in, const int* in_sizes, int n_in,
                              void* d_out, int out_size, void* d_ws, size_t ws_size,
                              hipStream_t stream)
{
    const float* x  = (const float*)d_in[0];
    const float* Wq = (const float*)d_in[1];
    const float* Wk = (const float*)d_in[2];
    const float* Wv = (const float*)d_in[3];
    const float* Wo = (const float*)d_in[4];
    const float* wb = (const float*)d_in[5];
    // window (d_in[6]) is the constant 128, baked in as W_.

    u16* Wth   = (u16*)d_ws;                 // 4*65536 = 262144
    u16* Wkl   = Wth + 262144;               // 65536
    u16* EWb   = Wkl + 65536;                // 655360
    u16* ekT   = EWb + 655360;               // 16777216
    u16* sigqT = ekT + 16777216;             // 8388608
    u16* yTD   = sigqT + 8388608;            // 8388608
    float* Sk  = (float*)(yTD + 8388608);    // 4096
    float* Sv  = Sk + 4096;                  // 4096

    hipMemsetAsync(Sk, 0, 2 * 4096 * sizeof(float), stream);

    aft_split_wT<<<dim3(4, 16), 256, 0, stream>>>(Wq, Wk, Wv, Wo, Wth, Wkl);
    aft_ewb<<<dim3(T_), 320, 0, stream>>>(wb, EWb);
    aft_qkv_mfma<<<dim3(M_ / 128, 4), 256, 0, stream>>>(x, Wth, Wkl, ekT, sigqT, Sk, Sv);
    aft_band_mfma<<<dim3(T_ / 64, B_ * 2), 256, 0, stream>>>(EWb, ekT, sigqT, Sk, Sv, yTD);
    aft_out_mfma<<<dim3(M_ / 64, 2), 256, 0, stream>>>(yTD, Wth + 3 * 65536, (float*)d_out);
}

// Round 8
// 201.949 us; speedup vs baseline: 1.3732x; 1.3732x over previous
//
#include <hip/hip_runtime.h>
#include <math.h>

#define B_ 16
#define T_ 2048
#define D_ 256
#define W_ 128
#define M_ (B_*T_)   // 32768

typedef __attribute__((ext_vector_type(8))) short bf16x8;
typedef __attribute__((ext_vector_type(4))) float f32x4;
typedef unsigned short u16;

static __device__ __forceinline__ u16 f32_bf16_rne(float f) {
    unsigned int u = __float_as_uint(f);
    u += 0x7FFF + ((u >> 16) & 1);
    return (u16)(u >> 16);
}
static __device__ __forceinline__ float bf16_f32(u16 h) {
    return __uint_as_float(((unsigned int)h) << 16);
}

// ---------------------------------------------------------------------------
// K0: transpose weights to bf16 [mat][n][k]: hi for all 4 mats; lo for Wk only.
// ---------------------------------------------------------------------------
__global__ __launch_bounds__(256) void aft_split_wT(
    const float* __restrict__ Wq, const float* __restrict__ Wk,
    const float* __restrict__ Wv, const float* __restrict__ Wo,
    u16* __restrict__ Wth, u16* __restrict__ Wkl)
{
    const float* Ws[4] = {Wq, Wk, Wv, Wo};
    const float* W = Ws[blockIdx.x];
    const int n  = blockIdx.y * 16 + (threadIdx.x >> 4);
    const int k0 = (threadIdx.x & 15) * 16;
    size_t obase = ((size_t)blockIdx.x * 256 + n) * 256 + k0;
    #pragma unroll 4
    for (int j = 0; j < 16; ++j) {
        float v = W[(size_t)(k0 + j) * 256 + n];
        u16 h = f32_bf16_rne(v);
        Wth[obase + j] = h;
        if (blockIdx.x == 1)
            Wkl[(size_t)n * 256 + k0 + j] = f32_bf16_rne(v - bf16_f32(h));
    }
}

// ---------------------------------------------------------------------------
// K0b: banded EW precompute. EWb[t][j], j in [0,320): exp(wb[t][s])-1 inside
// band else 0, s = (t & ~63) - 128 + j.  bf16.
// ---------------------------------------------------------------------------
__global__ void aft_ewb(const float* __restrict__ wb, u16* __restrict__ EWb)
{
    const int t = blockIdx.x;
    const int j = threadIdx.x;   // blockDim = 320
    const int s = (t & ~63) - 128 + j;
    const int dlt = s - t;
    float v = 0.f;
    if (s >= 0 && s < T_ && dlt > -W_ && dlt < W_)
        v = expf(wb[(size_t)t * T_ + s]) - 1.0f;
    EWb[(size_t)t * 320 + j] = f32_bf16_rne(v);
}

// ---------------------------------------------------------------------------
// K1: QKV projections.  q = xh*Wqh, k = 3-term split, v = xh*Wvh.
// 128 rows x 64 cols x 3 mats per block.  NO atomics (R7 post-mortem:
// 524K contended device atomics cost ~50 us) -- sums done by K2.
// ---------------------------------------------------------------------------
__global__ __launch_bounds__(256) void aft_qkv_mfma(
    const float* __restrict__ x,
    const u16* __restrict__ Wth, const u16* __restrict__ Wkl,
    u16* __restrict__ ekT, u16* __restrict__ sigqT)
{
    __shared__ alignas(16) u16 sm[20480];   // 40 KiB
    u16* Ah = sm;              // [128][40]
    u16* Al = sm + 5120;
    u16* Bs = sm + 10240;      // [4][64][40]: Wqh, Wkh, Wkl, Wvh
    u16* Tr = sm;              // [64][136] epilogue reuse

    const int tid  = threadIdx.x;
    const int row0 = blockIdx.x * 128;
    const int col0 = blockIdx.y * 64;
    const int b    = row0 >> 11;
    const int t0g  = row0 & (T_ - 1);
    const int lane = tid & 63;
    const int wid  = tid >> 6;
    const int wm   = (wid & 1) * 64;
    const int wn   = (wid >> 1) * 32;
    const int qd   = lane >> 4;
    const int r    = lane & 15;

    f32x4 accq[4][2], acck[4][2], accv[4][2];
    #pragma unroll
    for (int i = 0; i < 4; ++i)
        #pragma unroll
        for (int j = 0; j < 2; ++j) {
            accq[i][j] = (f32x4){0.f, 0.f, 0.f, 0.f};
            acck[i][j] = accq[i][j];
            accv[i][j] = accq[i][j];
        }

    const int am   = tid >> 1;          // 0..127
    const int akh  = (tid & 1) * 16;    // 0 / 16
    const int brow = tid >> 2;          // 0..63
    const int bseg = (tid & 3) * 8;     // 0,8,16,24

    for (int k0 = 0; k0 < D_; k0 += 32) {
        // stage A: fp32 x -> bf16 hi/lo in-kernel
        {
            size_t g = (size_t)(row0 + am) * D_ + k0 + akh;
            union { ushort4 s4[4]; u16 h[16]; } H, L;
            #pragma unroll
            for (int c = 0; c < 4; ++c) {
                float4 v = *(const float4*)&x[g + c * 4];
                float vv[4] = {v.x, v.y, v.z, v.w};
                #pragma unroll
                for (int e = 0; e < 4; ++e) {
                    u16 h = f32_bf16_rne(vv[e]);
                    H.h[c * 4 + e] = h;
                    L.h[c * 4 + e] = f32_bf16_rne(vv[e] - bf16_f32(h));
                }
            }
            *(ushort4*)&Ah[am * 40 + akh]      = H.s4[0];
            *(ushort4*)&Ah[am * 40 + akh + 4]  = H.s4[1];
            *(ushort4*)&Ah[am * 40 + akh + 8]  = H.s4[2];
            *(ushort4*)&Ah[am * 40 + akh + 12] = H.s4[3];
            *(ushort4*)&Al[am * 40 + akh]      = L.s4[0];
            *(ushort4*)&Al[am * 40 + akh + 4]  = L.s4[1];
            *(ushort4*)&Al[am * 40 + akh + 8]  = L.s4[2];
            *(ushort4*)&Al[am * 40 + akh + 12] = L.s4[3];
        }
        // stage B: Wqh, Wkh, Wkl, Wvh  (64 rows x 32 k each)
        {
            size_t nrow = (size_t)(col0 + brow) * 256 + k0 + bseg;
            uint4 vq  = *(const uint4*)&Wth[nrow];
            uint4 vkh = *(const uint4*)&Wth[65536 + nrow];
            uint4 vkl = *(const uint4*)&Wkl[nrow];
            uint4 vv  = *(const uint4*)&Wth[2 * 65536 + nrow];
            *(uint4*)&Bs[0 * 2560 + brow * 40 + bseg] = vq;
            *(uint4*)&Bs[1 * 2560 + brow * 40 + bseg] = vkh;
            *(uint4*)&Bs[2 * 2560 + brow * 40 + bseg] = vkl;
            *(uint4*)&Bs[3 * 2560 + brow * 40 + bseg] = vv;
        }
        __syncthreads();

        bf16x8 ah[4], al[4];
        #pragma unroll
        for (int mf = 0; mf < 4; ++mf) {
            ah[mf] = *(const bf16x8*)&Ah[(wm + mf * 16 + r) * 40 + qd * 8];
            al[mf] = *(const bf16x8*)&Al[(wm + mf * 16 + r) * 40 + qd * 8];
        }
        #pragma unroll
        for (int nf = 0; nf < 2; ++nf) {
            int br = (wn + nf * 16 + r) * 40 + qd * 8;
            bf16x8 bq  = *(const bf16x8*)&Bs[br];
            bf16x8 bkh = *(const bf16x8*)&Bs[2560 + br];
            bf16x8 bkl = *(const bf16x8*)&Bs[5120 + br];
            bf16x8 bv  = *(const bf16x8*)&Bs[7680 + br];
            #pragma unroll
            for (int mf = 0; mf < 4; ++mf) {
                accq[mf][nf] = __builtin_amdgcn_mfma_f32_16x16x32_bf16(ah[mf], bq,  accq[mf][nf], 0, 0, 0);
                acck[mf][nf] = __builtin_amdgcn_mfma_f32_16x16x32_bf16(ah[mf], bkh, acck[mf][nf], 0, 0, 0);
                acck[mf][nf] = __builtin_amdgcn_mfma_f32_16x16x32_bf16(ah[mf], bkl, acck[mf][nf], 0, 0, 0);
                acck[mf][nf] = __builtin_amdgcn_mfma_f32_16x16x32_bf16(al[mf], bkh, acck[mf][nf], 0, 0, 0);
                accv[mf][nf] = __builtin_amdgcn_mfma_f32_16x16x32_bf16(ah[mf], bv,  accv[mf][nf], 0, 0, 0);
            }
        }
        __syncthreads();
    }

    // epilogue: 3 LDS-transpose rounds (ek, ekv, sigq) -> global bf16
    const int dl_r = tid >> 2;            // 0..63
    const int tseg = (tid & 3) * 32;      // 0..96
    #pragma unroll
    for (int round = 0; round < 3; ++round) {
        __syncthreads();
        #pragma unroll
        for (int mf = 0; mf < 4; ++mf) {
            #pragma unroll
            for (int nf = 0; nf < 2; ++nf) {
                ushort4 o;
                float vals[4];
                #pragma unroll
                for (int reg = 0; reg < 4; ++reg) {
                    if (round == 0)      vals[reg] = expf(acck[mf][nf][reg]);
                    else if (round == 1) vals[reg] = expf(acck[mf][nf][reg]) * accv[mf][nf][reg];
                    else                 vals[reg] = 1.f / (1.f + expf(-accq[mf][nf][reg]));
                }
                o.x = f32_bf16_rne(vals[0]); o.y = f32_bf16_rne(vals[1]);
                o.z = f32_bf16_rne(vals[2]); o.w = f32_bf16_rne(vals[3]);
                int dl = wn + nf * 16 + r;
                int tt = wm + mf * 16 + qd * 4;
                *(ushort4*)&Tr[dl * 136 + tt] = o;
            }
        }
        __syncthreads();
        u16* dst;
        if (round == 0)      dst = ekT   + ((size_t)(b * 512 + col0 + dl_r)) * 2048;
        else if (round == 1) dst = ekT   + ((size_t)(b * 512 + 256 + col0 + dl_r)) * 2048;
        else                 dst = sigqT + ((size_t)(b * 256 + col0 + dl_r)) * 2048;
        dst += t0g + tseg;
        const u16* srcp = &Tr[dl_r * 136 + tseg];
        #pragma unroll
        for (int i = 0; i < 4; ++i)
            *(uint4*)&dst[i * 8] = *(const uint4*)&srcp[i * 8];
    }
}

// ---------------------------------------------------------------------------
// K2: row sums of ekT -> Sk (n<256), Sv (n>=256).  One wave per row, plain
// stores (no atomics, no memset needed).
// ---------------------------------------------------------------------------
__global__ __launch_bounds__(256) void aft_sums(
    const u16* __restrict__ ekT, float* __restrict__ Sk, float* __restrict__ Sv)
{
    const int wid  = threadIdx.x >> 6;
    const int lane = threadIdx.x & 63;
    const int row  = blockIdx.x * 4 + wid;   // 0..8191
    const int b = row >> 9, n = row & 511;
    const u16* p = ekT + (size_t)row * 2048 + lane * 32;
    float s = 0.f;
    #pragma unroll
    for (int c = 0; c < 4; ++c) {
        union { uint4 v; u16 h[8]; } u;
        u.v = *(const uint4*)&p[c * 8];
        #pragma unroll
        for (int i = 0; i < 8; ++i) s += bf16_f32(u.h[i]);
    }
    #pragma unroll
    for (int off = 32; off >= 1; off >>= 1) s += __shfl_down(s, off, 64);
    if (lane == 0) {
        if (n < 256) Sk[b * 256 + n] = s;
        else         Sv[b * 256 + n - 256] = s;
    }
}

// ---------------------------------------------------------------------------
// K3: banded num/den via bf16 MFMA.  Block = 64 t x 128 d; wave 64t x 32d
// holds num+den.  Epilogue: y = sig(q)*(Sv+num)/(Sk+den) -> y[b][t][d] bf16.
// ---------------------------------------------------------------------------
__global__ __launch_bounds__(256) void aft_band_mfma(
    const u16* __restrict__ EWb, const u16* __restrict__ ekT,
    const u16* __restrict__ sigqT,
    const float* __restrict__ Sk, const float* __restrict__ Sv,
    u16* __restrict__ yTD)
{
    __shared__ alignas(16) u16 sm[12800];
    u16* Aw  = sm;          // [64][40]
    u16* Bkv = sm + 2560;   // [256][40] : rows 0..127 ek, 128..255 ekv

    const int tid  = threadIdx.x;
    const int t0   = blockIdx.x * 64;
    const int b    = blockIdx.y >> 1;
    const int dh   = (blockIdx.y & 1) * 128;
    const int lane = tid & 63;
    const int wid  = tid >> 6;
    const int wn   = wid * 32;
    const int qd   = lane >> 4;
    const int r    = lane & 15;

    f32x4 accn[4][2], accd[4][2];
    #pragma unroll
    for (int i = 0; i < 4; ++i)
        #pragma unroll
        for (int j = 0; j < 2; ++j) {
            accn[i][j] = (f32x4){0.f, 0.f, 0.f, 0.f};
            accd[i][j] = (f32x4){0.f, 0.f, 0.f, 0.f};
        }

    const int atl = tid >> 2;          // 0..63
    const int ak8 = (tid & 3) * 8;     // 0,8,16,24

    for (int c = 0; c < 10; ++c) {
        const int sc = t0 - 128 + c * 32;
        if (sc < 0 || sc >= T_) continue;   // uniform per block; EW there is 0
        __syncthreads();
        *(uint4*)&Aw[atl * 40 + ak8] =
            *(const uint4*)&EWb[(size_t)(t0 + atl) * 320 + c * 32 + ak8];
        #pragma unroll
        for (int rr = 0; rr < 4; ++rr) {
            int nl = rr * 64 + atl;                        // 0..255
            int n  = (nl < 128) ? (dh + nl) : (256 + dh + nl - 128);
            *(uint4*)&Bkv[nl * 40 + ak8] =
                *(const uint4*)&ekT[((size_t)(b * 512) + n) * 2048 + sc + ak8];
        }
        __syncthreads();

        bf16x8 af[4];
        #pragma unroll
        for (int mf = 0; mf < 4; ++mf)
            af[mf] = *(const bf16x8*)&Aw[(mf * 16 + r) * 40 + qd * 8];
        #pragma unroll
        for (int nf = 0; nf < 2; ++nf) {
            bf16x8 be = *(const bf16x8*)&Bkv[(wn + nf * 16 + r) * 40 + qd * 8];
            bf16x8 bv = *(const bf16x8*)&Bkv[(128 + wn + nf * 16 + r) * 40 + qd * 8];
            #pragma unroll
            for (int mf = 0; mf < 4; ++mf) {
                accd[mf][nf] = __builtin_amdgcn_mfma_f32_16x16x32_bf16(af[mf], be, accd[mf][nf], 0, 0, 0);
                accn[mf][nf] = __builtin_amdgcn_mfma_f32_16x16x32_bf16(af[mf], bv, accn[mf][nf], 0, 0, 0);
            }
        }
    }

    // epilogue: y into LDS [t_local][136] then coalesced store to y[b][t][d]
    __syncthreads();
    u16* Ly = sm;    // [64][136]
    #pragma unroll
    for (int nf = 0; nf < 2; ++nf) {
        const int dl = wn + nf * 16 + r;
        const int d  = dh + dl;
        const float skq = Sk[(b << 8) + d];
        const float svq = Sv[(b << 8) + d];
        #pragma unroll
        for (int mf = 0; mf < 4; ++mf) {
            const int tt = t0 + mf * 16 + qd * 4;
            size_t off = ((size_t)(b << 8) + d) * 2048 + tt;
            ushort4 sg = *(const ushort4*)&sigqT[off];
            float s4[4] = {bf16_f32(sg.x), bf16_f32(sg.y), bf16_f32(sg.z), bf16_f32(sg.w)};
            #pragma unroll
            for (int reg = 0; reg < 4; ++reg) {
                float y = s4[reg] * (svq + accn[mf][nf][reg]) / (skq + accd[mf][nf][reg]);
                Ly[(mf * 16 + qd * 4 + reg) * 136 + dl] = f32_bf16_rne(y);
            }
        }
    }
    __syncthreads();
    {
        const int tl  = tid >> 2;          // 0..63
        const int ds4 = (tid & 3) * 32;    // 0..96
        u16* dst = yTD + ((size_t)b * 2048 + t0 + tl) * 256 + dh + ds4;
        #pragma unroll
        for (int i = 0; i < 4; ++i)
            *(uint4*)&dst[i * 8] = *(const uint4*)&Ly[tl * 136 + ds4 + i * 8];
    }
}

// ---------------------------------------------------------------------------
// K4: out = y @ Wo, single-bf16 both sides.  64 rows x 128 cols per block,
// grid (512, 2).  A staged from y[b][t][d] with vector loads/writes.
// ---------------------------------------------------------------------------
__global__ __launch_bounds__(256) void aft_out_mfma(
    const u16* __restrict__ yTD, const u16* __restrict__ Woth,
    float* __restrict__ out)
{
    __shared__ alignas(16) u16 sm[7680];
    u16* As = sm;           // [64][40]
    u16* Bh = sm + 2560;    // [128][40]

    const int tid  = threadIdx.x;
    const int row0 = blockIdx.x * 64;
    const int col0 = blockIdx.y * 128;
    const int lane = tid & 63;
    const int wid  = tid >> 6;
    const int wn   = wid * 32;
    const int qd   = lane >> 4;
    const int r    = lane & 15;

    f32x4 acc[4][2];
    #pragma unroll
    for (int i = 0; i < 4; ++i)
        #pragma unroll
        for (int j = 0; j < 2; ++j)
            acc[i][j] = (f32x4){0.f, 0.f, 0.f, 0.f};

    const int arow = tid >> 2;          // 0..63
    const int aseg = (tid & 3) * 8;
    const int brw  = tid >> 1;          // 0..127
    const int bsg  = (tid & 1) * 16;

    for (int k0 = 0; k0 < D_; k0 += 32) {
        {
            uint4 v = *(const uint4*)&yTD[(size_t)(row0 + arow) * 256 + k0 + aseg];
            *(uint4*)&As[arow * 40 + aseg] = v;
        }
        {
            size_t g = (size_t)(col0 + brw) * 256 + k0 + bsg;
            uint4 v0 = *(const uint4*)&Woth[g];
            uint4 v1 = *(const uint4*)&Woth[g + 8];
            *(uint4*)&Bh[brw * 40 + bsg]     = v0;
            *(uint4*)&Bh[brw * 40 + bsg + 8] = v1;
        }
        __syncthreads();

        bf16x8 af[4];
        #pragma unroll
        for (int mf = 0; mf < 4; ++mf)
            af[mf] = *(const bf16x8*)&As[(mf * 16 + r) * 40 + qd * 8];
        #pragma unroll
        for (int nf = 0; nf < 2; ++nf) {
            bf16x8 bh = *(const bf16x8*)&Bh[(wn + nf * 16 + r) * 40 + qd * 8];
            #pragma unroll
            for (int mf = 0; mf < 4; ++mf)
                acc[mf][nf] = __builtin_amdgcn_mfma_f32_16x16x32_bf16(af[mf], bh, acc[mf][nf], 0, 0, 0);
        }
        __syncthreads();
    }

    #pragma unroll
    for (int mf = 0; mf < 4; ++mf)
        #pragma unroll
        for (int nf = 0; nf < 2; ++nf)
            #pragma unroll
            for (int reg = 0; reg < 4; ++reg) {
                int mrow = row0 + mf * 16 + qd * 4 + reg;
                int ncol = col0 + wn + nf * 16 + r;
                out[(size_t)mrow * D_ + ncol] = acc[mf][nf][reg];
            }
}

extern "C" void kernel_launch(void* const* d_in, const int* in_sizes, int n_in,
                              void* d_out, int out_size, void* d_ws, size_t ws_size,
                              hipStream_t stream)
{
    const float* x  = (const float*)d_in[0];
    const float* Wq = (const float*)d_in[1];
    const float* Wk = (const float*)d_in[2];
    const float* Wv = (const float*)d_in[3];
    const float* Wo = (const float*)d_in[4];
    const float* wb = (const float*)d_in[5];
    // window (d_in[6]) is the constant 128, baked in as W_.

    u16* Wth   = (u16*)d_ws;                 // 4*65536 = 262144
    u16* Wkl   = Wth + 262144;               // 65536
    u16* EWb   = Wkl + 65536;                // 655360
    u16* ekT   = EWb + 655360;               // 16777216
    u16* sigqT = ekT + 16777216;             // 8388608
    u16* yTD   = sigqT + 8388608;            // 8388608
    float* Sk  = (float*)(yTD + 8388608);    // 4096
    float* Sv  = Sk + 4096;                  // 4096

    aft_split_wT<<<dim3(4, 16), 256, 0, stream>>>(Wq, Wk, Wv, Wo, Wth, Wkl);
    aft_ewb<<<dim3(T_), 320, 0, stream>>>(wb, EWb);
    aft_qkv_mfma<<<dim3(M_ / 128, 4), 256, 0, stream>>>(x, Wth, Wkl, ekT, sigqT);
    aft_sums<<<dim3(8192 / 4), 256, 0, stream>>>(ekT, Sk, Sv);
    aft_band_mfma<<<dim3(T_ / 64, B_ * 2), 256, 0, stream>>>(EWb, ekT, sigqT, Sk, Sv, yTD);
    aft_out_mfma<<<dim3(M_ / 64, 2), 256, 0, stream>>>(yTD, Wth + 3 * 65536, (float*)d_out);
}